// Round 4
// baseline (44902.606 us; speedup 1.0000x reference)
//
#include <hip/hip_runtime.h>
#include <hip/hip_bf16.h>
#include <hip/hip_cooperative_groups.h>

namespace cg = cooperative_groups;

#define BB 256
#define TT 1024
#define DIN 64
#define HH 1024
#define NL 3
#define ALPHA 0.5f
#define SBUF (NL * BB * HH)

typedef __attribute__((ext_vector_type(8))) short bf16x8;
typedef __attribute__((ext_vector_type(4))) float f32x4;
typedef __attribute__((ext_vector_type(4))) unsigned short u16x4;

// ---- workspace byte offsets ----
static const size_t XT_OFF  = 0;          // bf16 [T][B][DIN]   33,554,432 B
static const size_t WB_OFF  = 33554432;   // bf16 weights       10,616,832 B
static const size_t S16_OFF = 44171264;   // bf16 [2][L][B][H]   3,145,728 B
static const size_t S32_OFF = 47316992;   // f32  [L][B][H]      3,145,728 B

#define WIN0_E   0
#define WIN12_E  65536
#define WRES_E   2162688

// ---------------- weight fp32 -> bf16 convert ----------------
__global__ void convert_kernel(const float* __restrict__ w_in0,
                               const float* __restrict__ w_in_rest,
                               const float* __restrict__ w_res,
                               __hip_bfloat16* __restrict__ Wb)
{
    const size_t total = 65536ull + 2097152ull + 3145728ull;
    for (size_t i = (size_t)blockIdx.x * blockDim.x + threadIdx.x; i < total;
         i += (size_t)gridDim.x * blockDim.x) {
        float v;
        if (i < 65536)            v = w_in0[i];
        else if (i < 2162688)     v = w_in_rest[i - 65536];
        else                      v = w_res[i - 2162688];
        Wb[i] = __float2bfloat16(v);
    }
}

// ---------------- x [B][T][D] fp32 -> xT [T][B][D] bf16 ----------------
__global__ void transpose_x_kernel(const float* __restrict__ x,
                                   unsigned short* __restrict__ xT)
{
    const size_t n4 = (size_t)BB * TT * DIN / 4;
    for (size_t i = (size_t)blockIdx.x * blockDim.x + threadIdx.x; i < n4;
         i += (size_t)gridDim.x * blockDim.x) {
        size_t flat = i * 4;
        int d = (int)(flat & (DIN - 1));
        int t = (int)((flat >> 6) & (TT - 1));
        int b = (int)(flat >> 16);
        const float4 v = reinterpret_cast<const float4*>(x)[i];
        __hip_bfloat16 h0 = __float2bfloat16(v.x);
        __hip_bfloat16 h1 = __float2bfloat16(v.y);
        __hip_bfloat16 h2 = __float2bfloat16(v.z);
        __hip_bfloat16 h3 = __float2bfloat16(v.w);
        u16x4 pk;
        pk.x = *(unsigned short*)&h0; pk.y = *(unsigned short*)&h1;
        pk.z = *(unsigned short*)&h2; pk.w = *(unsigned short*)&h3;
        *reinterpret_cast<u16x4*>(xT + ((size_t)t * BB + b) * DIN + d) = pk;
    }
}

__device__ __forceinline__ float tanh_fast(float x) {
    float e = __expf(2.0f * x);       // inf-safe: x>>0 -> 1, x<<0 -> -1
    return 1.0f - 2.0f / (e + 1.0f);
}

// B in LDS, k-major blocks: off = ((k/8)*32 + col)*16 bytes  (conflict-free b128 reads,
// immediate-offset addressable). Bp is the per-lane base: ((kq>>3)*32 + ar)*16.
template <int KTOT>
__device__ __forceinline__ void gemm_lds(const unsigned short* __restrict__ A0,
                                         const unsigned short* __restrict__ A1,
                                         const char* __restrict__ Bp,
                                         f32x4& a00, f32x4& a01, f32x4& a10, f32x4& a11)
{
#pragma unroll 8
    for (int k = 0; k < KTOT; k += 32) {
        bf16x8 a0 = *(const bf16x8*)(A0 + k);
        bf16x8 a1 = *(const bf16x8*)(A1 + k);
        bf16x8 b0 = *(const bf16x8*)(Bp + k * 64);
        bf16x8 b1 = *(const bf16x8*)(Bp + k * 64 + 256);
        a00 = __builtin_amdgcn_mfma_f32_16x16x32_bf16(a0, b0, a00, 0, 0, 0);
        a01 = __builtin_amdgcn_mfma_f32_16x16x32_bf16(a0, b1, a01, 0, 0, 0);
        a10 = __builtin_amdgcn_mfma_f32_16x16x32_bf16(a1, b0, a10, 0, 0, 0);
        a11 = __builtin_amdgcn_mfma_f32_16x16x32_bf16(a1, b1, a11, 0, 0, 0);
    }
}

// Persistent cooperative kernel: 192 wgs = 2 batch-halves x (3 layers x 32 col-tiles).
// Each wg: weights for its 32 cols in LDS (staged once), fp32 state master in regs,
// T-loop with one grid.sync per super-step (layer-skewed pipeline, t = s - l).
__global__ __launch_bounds__(256, 1) void esn_main(
    const unsigned short* __restrict__ xT,
    const unsigned short* __restrict__ Wb,
    unsigned short* __restrict__ S16,
    float* __restrict__ S32)
{
    __shared__ char Blds[131072];   // part0: W_in slice, part1: W_res slice (64 KB each)

    const int wg  = blockIdx.x;           // 0..191
    const int bi  = wg / 96;
    const int rem = wg - bi * 96;
    const int l   = rem >> 5;
    const int ni  = rem & 31;
    const int n0  = ni * 32;

    const int tid  = threadIdx.x;
    const int lane = tid & 63;
    const int w    = tid >> 6;

    // ---- stage weight slice into LDS, once ----
    {
        const unsigned short* gWin = (l == 0) ? (Wb + WIN0_E)
                                              : (Wb + WIN12_E + (size_t)(l - 1) * HH * HH);
        const int kin  = (l == 0) ? DIN : HH;
        const int nblk = 32 * (kin >> 3);
        for (int idx = tid; idx < nblk; idx += 256) {
            int c   = idx & 31;
            int kb8 = idx >> 5;
            bf16x8 v = *(const bf16x8*)(gWin + (size_t)(n0 + c) * kin + kb8 * 8);
            *(bf16x8*)(Blds + (kb8 * 32 + c) * 16) = v;
        }
        const unsigned short* gWres = Wb + WRES_E + (size_t)l * HH * HH;
        for (int idx = tid; idx < 32 * 128; idx += 256) {
            int c   = idx & 31;
            int kb8 = idx >> 5;
            bf16x8 v = *(const bf16x8*)(gWres + (size_t)(n0 + c) * HH + kb8 * 8);
            *(bf16x8*)(Blds + 65536 + (kb8 * 32 + c) * 16) = v;
        }
    }
    __syncthreads();

    const int ar = lane & 15;
    const int kq = (lane >> 4) << 3;
    const int m0 = bi * 128 + w * 32;
    const char* BpIn  = Blds + ((kq >> 3) * 32 + ar) * 16;
    const char* BpRes = BpIn + 65536;
    const int rb = (lane >> 4) << 2;
    const int cc = lane & 15;

    // fp32 state master lives in registers for the whole T loop
    float mst[2][2][4];
#pragma unroll
    for (int i = 0; i < 2; ++i)
#pragma unroll
        for (int j = 0; j < 2; ++j)
#pragma unroll
            for (int r = 0; r < 4; ++r) mst[i][j][r] = 0.f;

    cg::grid_group grid = cg::this_grid();

    for (int s = 0; s < TT + NL - 1; ++s) {
        const int t = s - l;
        const unsigned short* Sc = S16 + (size_t)(s & 1) * SBUF;
        unsigned short*       Sn = S16 + (size_t)((s + 1) & 1) * SBUF;
        if (t >= 0 && t < TT) {
            f32x4 a00 = {0.f, 0.f, 0.f, 0.f};
            f32x4 a01 = a00, a10 = a00, a11 = a00;
            // part 1: state_l @ W_res[l]^T  (K = H)
            {
                const unsigned short* A  = Sc + (size_t)l * (BB * HH);
                const unsigned short* A0 = A + (size_t)(m0 + ar) * HH + kq;
                gemm_lds<HH>(A0, A0 + 16 * HH, BpRes, a00, a01, a10, a11);
            }
            // part 0: cur @ W_in[l]^T
            if (l == 0) {
                const unsigned short* A  = xT + (size_t)t * (BB * DIN);
                const unsigned short* A0 = A + (size_t)(m0 + ar) * DIN + kq;
                gemm_lds<DIN>(A0, A0 + 16 * DIN, BpIn, a00, a01, a10, a11);
            } else {
                const unsigned short* A  = Sc + (size_t)(l - 1) * (BB * HH);
                const unsigned short* A0 = A + (size_t)(m0 + ar) * HH + kq;
                gemm_lds<HH>(A0, A0 + 16 * HH, BpIn, a00, a01, a10, a11);
            }
            // epilogue: leaky update (fp32 master in regs), publish bf16
#pragma unroll
            for (int i = 0; i < 2; ++i)
#pragma unroll
            for (int j = 0; j < 2; ++j) {
                f32x4 acc = (i == 0) ? ((j == 0) ? a00 : a01) : ((j == 0) ? a10 : a11);
#pragma unroll
                for (int r = 0; r < 4; ++r) {
                    float hnew = (1.0f - ALPHA) * mst[i][j][r] + ALPHA * tanh_fast(acc[r]);
                    mst[i][j][r] = hnew;
                    int b = m0 + i * 16 + rb + r;
                    int h = n0 + j * 16 + cc;
                    __hip_bfloat16 hb = __float2bfloat16(hnew);
                    Sn[((size_t)l * BB + b) * HH + h] = *(unsigned short*)&hb;
                }
            }
        }
        grid.sync();
    }

    // final fp32 state dump for the readout
#pragma unroll
    for (int i = 0; i < 2; ++i)
#pragma unroll
    for (int j = 0; j < 2; ++j)
#pragma unroll
    for (int r = 0; r < 4; ++r) {
        int b = m0 + i * 16 + rb + r;
        int h = n0 + j * 16 + cc;
        S32[((size_t)l * BB + b) * HH + h] = mst[i][j][r];
    }
}

// ---------------- readout ----------------
__global__ void out_kernel(const float* __restrict__ S32,
                           const float* __restrict__ w_out,
                           const float* __restrict__ b_out,
                           float* __restrict__ out)
{
    int b = blockIdx.x;
    int tid = threadIdx.x;
    float p = 0.f;
    for (int idx = tid; idx < NL * HH; idx += 256) {
        int l = idx >> 10;
        int h = idx & (HH - 1);
        p += S32[((size_t)l * BB + b) * HH + h] * w_out[idx];
    }
    __shared__ float red[256];
    red[tid] = p;
    __syncthreads();
    for (int off = 128; off > 0; off >>= 1) {
        if (tid < off) red[tid] += red[tid + off];
        __syncthreads();
    }
    if (tid == 0) out[b] = red[0] + b_out[0];
}

extern "C" void kernel_launch(void* const* d_in, const int* in_sizes, int n_in,
                              void* d_out, int out_size, void* d_ws, size_t ws_size,
                              hipStream_t stream)
{
    const float* x         = (const float*)d_in[0];
    const float* W_in0     = (const float*)d_in[1];
    const float* W_in_rest = (const float*)d_in[2];
    const float* W_res     = (const float*)d_in[3];
    const float* w_out     = (const float*)d_in[4];
    const float* b_out     = (const float*)d_in[5];

    char* ws = (char*)d_ws;
    const unsigned short* xTp  = (const unsigned short*)(ws + XT_OFF);
    __hip_bfloat16*       Wbh  = (__hip_bfloat16*)(ws + WB_OFF);
    const unsigned short* Wbp  = (const unsigned short*)(ws + WB_OFF);
    unsigned short*       S16p = (unsigned short*)(ws + S16_OFF);
    float*                S32p = (float*)(ws + S32_OFF);

    convert_kernel<<<4096, 256, 0, stream>>>(W_in0, W_in_rest, W_res, Wbh);
    transpose_x_kernel<<<4096, 256, 0, stream>>>(x, (unsigned short*)(ws + XT_OFF));
    hipMemsetAsync(ws + S16_OFF, 0, 3145728, stream);   // zero both S16 parity buffers

    void* args[] = { (void*)&xTp, (void*)&Wbp, (void*)&S16p, (void*)&S32p };
    hipLaunchCooperativeKernel((const void*)esn_main, dim3(192), dim3(256),
                               args, 0, stream);

    out_kernel<<<BB, 256, 0, stream>>>(S32p, w_out, b_out, (float*)d_out);
}

// Round 7
// 27901.318 us; speedup vs baseline: 1.6093x; 1.6093x over previous
//
#include <hip/hip_runtime.h>
#include <hip/hip_bf16.h>

#define BB 256
#define TT 1024
#define DIN 64
#define HH 1024
#define NL 3
#define ALPHA 0.5f
#define SBUF (NL * BB * HH)
#define NWG 192

typedef __attribute__((ext_vector_type(8))) short bf16x8;
typedef __attribute__((ext_vector_type(4))) float f32x4;
typedef __attribute__((ext_vector_type(4))) unsigned short u16x4;

// ---- workspace byte offsets ----
static const size_t XT_OFF  = 0;          // bf16 [T][B][DIN]   33,554,432 B
static const size_t WB_OFF  = 33554432;   // bf16 weights       10,616,832 B
static const size_t S16_OFF = 44171264;   // bf16 [2][L][B][H]   3,145,728 B
static const size_t S32_OFF = 47316992;   // f32  [L][B][H]      3,145,728 B
static const size_t BAR_OFF = 50462720;   // barrier block            256 B

#define WIN0_E   0
#define WIN12_E  65536
#define WRES_E   2162688

// ---------------- weight fp32 -> bf16 convert ----------------
__global__ void convert_kernel(const float* __restrict__ w_in0,
                               const float* __restrict__ w_in_rest,
                               const float* __restrict__ w_res,
                               __hip_bfloat16* __restrict__ Wb)
{
    const size_t total = 65536ull + 2097152ull + 3145728ull;
    for (size_t i = (size_t)blockIdx.x * blockDim.x + threadIdx.x; i < total;
         i += (size_t)gridDim.x * blockDim.x) {
        float v;
        if (i < 65536)            v = w_in0[i];
        else if (i < 2162688)     v = w_in_rest[i - 65536];
        else                      v = w_res[i - 2162688];
        Wb[i] = __float2bfloat16(v);
    }
}

// ---------------- x [B][T][D] fp32 -> xT [T][B][D] bf16 ----------------
__global__ void transpose_x_kernel(const float* __restrict__ x,
                                   unsigned short* __restrict__ xT)
{
    const size_t n4 = (size_t)BB * TT * DIN / 4;
    for (size_t i = (size_t)blockIdx.x * blockDim.x + threadIdx.x; i < n4;
         i += (size_t)gridDim.x * blockDim.x) {
        size_t flat = i * 4;
        int d = (int)(flat & (DIN - 1));
        int t = (int)((flat >> 6) & (TT - 1));
        int b = (int)(flat >> 16);
        const float4 v = reinterpret_cast<const float4*>(x)[i];
        __hip_bfloat16 h0 = __float2bfloat16(v.x);
        __hip_bfloat16 h1 = __float2bfloat16(v.y);
        __hip_bfloat16 h2 = __float2bfloat16(v.z);
        __hip_bfloat16 h3 = __float2bfloat16(v.w);
        u16x4 pk;
        pk.x = *(unsigned short*)&h0; pk.y = *(unsigned short*)&h1;
        pk.z = *(unsigned short*)&h2; pk.w = *(unsigned short*)&h3;
        *reinterpret_cast<u16x4*>(xT + ((size_t)t * BB + b) * DIN + d) = pk;
    }
}

__device__ __forceinline__ float tanh_fast(float x) {
    float e = __expf(2.0f * x);       // inf-safe: x>>0 -> 1, x<<0 -> -1
    return 1.0f - 2.0f / (e + 1.0f);
}

// Lean grid barrier: monotonic generation, one leader atomic per wg.
// cnt at bar[0], gen at bar[32] (separate 128B lines).
// Release-add orders this wg's state writes; relaxed spin (bypassing atomic
// loads, s_sleep backoff); single acquire fence (L1+L2 inv) on exit.
__device__ __forceinline__ void grid_barrier(unsigned int* __restrict__ bar, int step)
{
    __syncthreads();
    if (threadIdx.x == 0) {
        const unsigned int want = (unsigned int)(step + 1);
        unsigned int old = __hip_atomic_fetch_add(bar, 1u, __ATOMIC_RELEASE,
                                                  __HIP_MEMORY_SCOPE_AGENT);
        if (old == (unsigned int)NWG * want - 1u) {
            __hip_atomic_store(bar + 32, want, __ATOMIC_RELEASE,
                               __HIP_MEMORY_SCOPE_AGENT);
        } else {
            while (__hip_atomic_load(bar + 32, __ATOMIC_RELAXED,
                                     __HIP_MEMORY_SCOPE_AGENT) < want)
                __builtin_amdgcn_s_sleep(2);
        }
        __builtin_amdgcn_fence(__ATOMIC_ACQUIRE, "agent");
    }
    __syncthreads();
}

// B in LDS, k-major blocks: off = ((k/8)*32 + col)*16 bytes (conflict-free b128).
template <int KTOT>
__device__ __forceinline__ void gemm_lds(const unsigned short* __restrict__ A0,
                                         const unsigned short* __restrict__ A1,
                                         const char* __restrict__ Bp,
                                         f32x4& a00, f32x4& a01, f32x4& a10, f32x4& a11)
{
#pragma unroll 8
    for (int k = 0; k < KTOT; k += 32) {
        bf16x8 a0 = *(const bf16x8*)(A0 + k);
        bf16x8 a1 = *(const bf16x8*)(A1 + k);
        bf16x8 b0 = *(const bf16x8*)(Bp + k * 64);
        bf16x8 b1 = *(const bf16x8*)(Bp + k * 64 + 256);
        a00 = __builtin_amdgcn_mfma_f32_16x16x32_bf16(a0, b0, a00, 0, 0, 0);
        a01 = __builtin_amdgcn_mfma_f32_16x16x32_bf16(a0, b1, a01, 0, 0, 0);
        a10 = __builtin_amdgcn_mfma_f32_16x16x32_bf16(a1, b0, a10, 0, 0, 0);
        a11 = __builtin_amdgcn_mfma_f32_16x16x32_bf16(a1, b1, a11, 0, 0, 0);
    }
}

// Persistent kernel: 192 wgs = 2 batch-halves x (3 layers x 32 col-tiles).
// Weights in LDS (staged once), fp32 state master in regs, custom barrier per step.
__global__ __launch_bounds__(256, 1) void esn_main(
    const unsigned short* __restrict__ xT,
    const unsigned short* __restrict__ Wb,
    unsigned short* __restrict__ S16,
    float* __restrict__ S32,
    unsigned int* __restrict__ bar)
{
    __shared__ char Blds[131072];   // part0: W_in slice, part1: W_res slice (64 KB each)

    const int wg  = blockIdx.x;           // 0..191
    const int bi  = wg / 96;
    const int rem = wg - bi * 96;
    const int l   = rem >> 5;
    const int ni  = rem & 31;
    const int n0  = ni * 32;

    const int tid  = threadIdx.x;
    const int lane = tid & 63;
    const int w    = tid >> 6;

    // ---- stage weight slice into LDS, once ----
    {
        const unsigned short* gWin = (l == 0) ? (Wb + WIN0_E)
                                              : (Wb + WIN12_E + (size_t)(l - 1) * HH * HH);
        const int kin  = (l == 0) ? DIN : HH;
        const int nblk = 32 * (kin >> 3);
        for (int idx = tid; idx < nblk; idx += 256) {
            int c   = idx & 31;
            int kb8 = idx >> 5;
            bf16x8 v = *(const bf16x8*)(gWin + (size_t)(n0 + c) * kin + kb8 * 8);
            *(bf16x8*)(Blds + (kb8 * 32 + c) * 16) = v;
        }
        const unsigned short* gWres = Wb + WRES_E + (size_t)l * HH * HH;
        for (int idx = tid; idx < 32 * 128; idx += 256) {
            int c   = idx & 31;
            int kb8 = idx >> 5;
            bf16x8 v = *(const bf16x8*)(gWres + (size_t)(n0 + c) * HH + kb8 * 8);
            *(bf16x8*)(Blds + 65536 + (kb8 * 32 + c) * 16) = v;
        }
    }
    __syncthreads();

    const int ar = lane & 15;
    const int kq = (lane >> 4) << 3;
    const int m0 = bi * 128 + w * 32;
    const char* BpIn  = Blds + ((kq >> 3) * 32 + ar) * 16;
    const char* BpRes = BpIn + 65536;
    const int rb = (lane >> 4) << 2;
    const int cc = lane & 15;

    // fp32 state master lives in registers for the whole T loop
    float mst[2][2][4];
#pragma unroll
    for (int i = 0; i < 2; ++i)
#pragma unroll
        for (int j = 0; j < 2; ++j)
#pragma unroll
            for (int r = 0; r < 4; ++r) mst[i][j][r] = 0.f;

    for (int s = 0; s < TT + NL - 1; ++s) {
        const int t = s - l;
        const unsigned short* Sc = S16 + (size_t)(s & 1) * SBUF;
        unsigned short*       Sn = S16 + (size_t)((s + 1) & 1) * SBUF;
        if (t >= 0 && t < TT) {
            f32x4 a00 = {0.f, 0.f, 0.f, 0.f};
            f32x4 a01 = a00, a10 = a00, a11 = a00;
            // part 1: state_l @ W_res[l]^T  (K = H)
            {
                const unsigned short* A  = Sc + (size_t)l * (BB * HH);
                const unsigned short* A0 = A + (size_t)(m0 + ar) * HH + kq;
                gemm_lds<HH>(A0, A0 + 16 * HH, BpRes, a00, a01, a10, a11);
            }
            // part 0: cur @ W_in[l]^T
            if (l == 0) {
                const unsigned short* A  = xT + (size_t)t * (BB * DIN);
                const unsigned short* A0 = A + (size_t)(m0 + ar) * DIN + kq;
                gemm_lds<DIN>(A0, A0 + 16 * DIN, BpIn, a00, a01, a10, a11);
            } else {
                const unsigned short* A  = Sc + (size_t)(l - 1) * (BB * HH);
                const unsigned short* A0 = A + (size_t)(m0 + ar) * HH + kq;
                gemm_lds<HH>(A0, A0 + 16 * HH, BpIn, a00, a01, a10, a11);
            }
            // epilogue: leaky update (fp32 master in regs), publish bf16
#pragma unroll
            for (int i = 0; i < 2; ++i)
#pragma unroll
            for (int j = 0; j < 2; ++j) {
                f32x4 acc = (i == 0) ? ((j == 0) ? a00 : a01) : ((j == 0) ? a10 : a11);
#pragma unroll
                for (int r = 0; r < 4; ++r) {
                    float hnew = (1.0f - ALPHA) * mst[i][j][r] + ALPHA * tanh_fast(acc[r]);
                    mst[i][j][r] = hnew;
                    int b = m0 + i * 16 + rb + r;
                    int h = n0 + j * 16 + cc;
                    __hip_bfloat16 hb = __float2bfloat16(hnew);
                    Sn[((size_t)l * BB + b) * HH + h] = *(unsigned short*)&hb;
                }
            }
        }
        grid_barrier(bar, s);
    }

    // final fp32 state dump for the readout
#pragma unroll
    for (int i = 0; i < 2; ++i)
#pragma unroll
    for (int j = 0; j < 2; ++j)
#pragma unroll
    for (int r = 0; r < 4; ++r) {
        int b = m0 + i * 16 + rb + r;
        int h = n0 + j * 16 + cc;
        S32[((size_t)l * BB + b) * HH + h] = mst[i][j][r];
    }
}

// ---------------- readout ----------------
__global__ void out_kernel(const float* __restrict__ S32,
                           const float* __restrict__ w_out,
                           const float* __restrict__ b_out,
                           float* __restrict__ out)
{
    int b = blockIdx.x;
    int tid = threadIdx.x;
    float p = 0.f;
    for (int idx = tid; idx < NL * HH; idx += 256) {
        int l = idx >> 10;
        int h = idx & (HH - 1);
        p += S32[((size_t)l * BB + b) * HH + h] * w_out[idx];
    }
    __shared__ float red[256];
    red[tid] = p;
    __syncthreads();
    for (int off = 128; off > 0; off >>= 1) {
        if (tid < off) red[tid] += red[tid + off];
        __syncthreads();
    }
    if (tid == 0) out[b] = red[0] + b_out[0];
}

extern "C" void kernel_launch(void* const* d_in, const int* in_sizes, int n_in,
                              void* d_out, int out_size, void* d_ws, size_t ws_size,
                              hipStream_t stream)
{
    const float* x         = (const float*)d_in[0];
    const float* W_in0     = (const float*)d_in[1];
    const float* W_in_rest = (const float*)d_in[2];
    const float* W_res     = (const float*)d_in[3];
    const float* w_out     = (const float*)d_in[4];
    const float* b_out     = (const float*)d_in[5];

    char* ws = (char*)d_ws;
    const unsigned short* xTp  = (const unsigned short*)(ws + XT_OFF);
    __hip_bfloat16*       Wbh  = (__hip_bfloat16*)(ws + WB_OFF);
    const unsigned short* Wbp  = (const unsigned short*)(ws + WB_OFF);
    unsigned short*       S16p = (unsigned short*)(ws + S16_OFF);
    float*                S32p = (float*)(ws + S32_OFF);
    unsigned int*         barp = (unsigned int*)(ws + BAR_OFF);

    convert_kernel<<<4096, 256, 0, stream>>>(W_in0, W_in_rest, W_res, Wbh);
    transpose_x_kernel<<<4096, 256, 0, stream>>>(x, (unsigned short*)(ws + XT_OFF));
    // zero S16 (both parity buffers) + S32 + barrier block in one contiguous memset
    hipMemsetAsync(ws + S16_OFF, 0, 6291712, stream);

    void* args[] = { (void*)&xTp, (void*)&Wbp, (void*)&S16p, (void*)&S32p, (void*)&barp };
    hipLaunchCooperativeKernel((const void*)esn_main, dim3(NWG), dim3(256),
                               args, 0, stream);

    out_kernel<<<BB, 256, 0, stream>>>(S32p, w_out, b_out, (float*)d_out);
}